// Round 7
// baseline (145.116 us; speedup 1.0000x reference)
//
#include <hip/hip_runtime.h>
#include <stdint.h>

#define DM 1024
#define LS 2048
#define RMS_EPS 1.1920928955078125e-07f
#define S2 0.0029296875f   // BC_SCALE^2 = 3/1024, exact in fp32

typedef __attribute__((ext_vector_type(8))) short bf16x8;
typedef __attribute__((ext_vector_type(4))) float f32x4;

__device__ __forceinline__ unsigned short f2bf(float f) {
  uint32_t u = __builtin_bit_cast(uint32_t, f);
  u += 0x7FFFu + ((u >> 16) & 1u);   // round-to-nearest-even
  return (unsigned short)(u >> 16);
}

// ---------------------------------------------------------------------------
// K0: pack B (64x1024) and C (64x1024) fp32 -> stacked bf16 [128][1024]
// ---------------------------------------------------------------------------
__global__ __launch_bounds__(256) void k0_prep(const float* __restrict__ B,
                                               const float* __restrict__ C,
                                               unsigned short* __restrict__ Bbf) {
  int i4 = blockIdx.x * 256 + threadIdx.x;          // 0..32767 float4s
  const float4* src = (i4 < 16384) ? (const float4*)B : (const float4*)C;
  float4 v = src[i4 & 16383];
  ushort4 o;
  o.x = f2bf(v.x); o.y = f2bf(v.y); o.z = f2bf(v.z); o.w = f2bf(v.w);
  ((ushort4*)Bbf)[i4] = o;
}

// ---------------------------------------------------------------------------
// KG v8: R0-k1's one-barrier free-run GEMM + v6's Kw epilogue.
// 512 blocks (b:4 x t-tile:128, XCD-chunk-swizzled) x 256 thr (4 waves),
// LDS 65.3 KB -> 2 blocks/CU.  Cols [t0-16, t0+16) (halo), M=128, K=1024.
// Phase S: ONE-SHOT stage u[1024][32] -> bf16 tile[128 k8][32] (64 KB),
//   coalesced 128B row segments; ONE barrier.  Swizzle: store col ^ kq
//   (kq = k8>>2 & 7) -> write AND read both hit the uniform bank floor.
// Phase G: free-run, NO barriers: per wave 32 its; af = global bf16x8 from
//   L2-resident Bbf (R0-proven pattern); bf = LDS b128; waves 2-3 (C-half)
//   skip cn=0 (halo cols: Cu never used there) -> 25% less MFMA.
// Epilogue (v6-proven): barrier; acc -> BuCu overlay; barrier; Kw recurrence
//   (t:16, p:16, shfl-xor reduce); 1 KB coalesced Kw write.
// ---------------------------------------------------------------------------
__global__ __launch_bounds__(256) void kg(const float* __restrict__ u,
                                          const unsigned short* __restrict__ Bbf,
                                          const float* __restrict__ A,
                                          float* __restrict__ Kwg) {
  const int wg = blockIdx.x;                    // 0..511
  const int sw = (wg & 7) * 64 + (wg >> 3);     // chunked XCD swizzle (bijective)
  const int b  = sw >> 7;
  const int t0 = (sw & 127) * 16;
  const int tid  = threadIdx.x;
  const int lane = tid & 63;
  const int w    = tid >> 6;                    // 0..3
  const int nn = lane & 15, q = lane >> 4;
  const float* ub = u + (size_t)b * DM * LS;

  __shared__ __align__(16) bf16x8 tile[128][32];    // 64 KB
  __shared__ float KwS[16][20];
  float (*BuCu)[132] = (float (*)[132])&tile[0][0]; // epilogue overlay 16.9 KB

  { // ---- Phase S: one-shot stage.  wave w: k in [256w, 256w+256). ----
    const int kq = lane >> 3;                   // 0..7 -> k8 bit 2..4
    const int lo = lane & 7;                    // 0..7 col-quads
    const int gcol = t0 - 16 + 4*lo;
    #pragma unroll
    for (int hh = 0; hh < 4; ++hh) {
      const int krow = 256*w + 32*kq + 8*hh;
      float4 vv[8];
      if (gcol >= 0) {
        #pragma unroll
        for (int r = 0; r < 8; ++r)             // 8 rows x 16B: 128B segments
          vv[r] = *(const float4*)(ub + (size_t)(krow + r) * LS + gcol);
      } else {
        #pragma unroll
        for (int r = 0; r < 8; ++r) vv[r] = make_float4(0.f, 0.f, 0.f, 0.f);
      }
      const int k8 = krow >> 3;                 // 32w + 4kq + hh
      #pragma unroll
      for (int c = 0; c < 4; ++c) {
        union { bf16x8 v; unsigned short s[8]; } t8;
        #pragma unroll
        for (int r = 0; r < 8; ++r) t8.s[r] = f2bf(((const float*)&vv[r])[c]);
        tile[k8][(4*lo + c) ^ kq] = t8.v;       // ^kq: uniform bank floor
      }
    }
  }
  __syncthreads();                              // the ONLY pre-compute barrier

  // ---- Phase G: free-run.  Wave w rows [32w,32w+32) (rt), cols cn. ----
  f32x4 acc[2][2] = {};                         // [rt][cn]
  const unsigned short* arow0 = Bbf + (size_t)(32*w + nn) * DM + 8*q;
  #pragma unroll 4
  for (int it = 0; it < 32; ++it) {
    const int sx = nn ^ (it & 7);               // read-side swizzle (k8>>2 = it)
    bf16x8 bf1 = tile[4*it + q][16 + sx];       // output cols [t0, t0+16)
    bf16x8 af0 = *(const bf16x8*)(arow0 + 32*it);
    bf16x8 af1 = *(const bf16x8*)(arow0 + (size_t)16*DM + 32*it);
    acc[0][1] = __builtin_amdgcn_mfma_f32_16x16x32_bf16(af0, bf1, acc[0][1], 0, 0, 0);
    acc[1][1] = __builtin_amdgcn_mfma_f32_16x16x32_bf16(af1, bf1, acc[1][1], 0, 0, 0);
    if (w < 2) {                                // halo cols need Bu only (rows<64)
      bf16x8 bf0 = tile[4*it + q][sx];
      acc[0][0] = __builtin_amdgcn_mfma_f32_16x16x32_bf16(af0, bf0, acc[0][0], 0, 0, 0);
      acc[1][0] = __builtin_amdgcn_mfma_f32_16x16x32_bf16(af1, bf0, acc[1][0], 0, 0, 0);
    }
  }
  __syncthreads();                              // all tile reads done

  // ---- epilogue: acc -> BuCu (overlay), C/D: col=lane&15, row=4q+reg ----
  #pragma unroll
  for (int rt = 0; rt < 2; ++rt)
    #pragma unroll
    for (int cn = 0; cn < 2; ++cn)
      *(f32x4*)&BuCu[16*cn + nn][32*w + 16*rt + 4*q] = acc[rt][cn];
  __syncthreads();

  { // ---- Kw[t][j] = S2 * sum_n Cu[t][n] A^j[n] Bu[t-j][n]  (v6-proven) ----
    const int t = tid >> 4, p = tid & 15;
    const float4 cu = *(const float4*)&BuCu[16 + t][64 + 4*p];
    const float4 aa = *(const float4*)(A + 4*p);
    float pw0 = cu.x * S2, pw1 = cu.y * S2, pw2 = cu.z * S2, pw3 = cu.w * S2;
    #pragma unroll
    for (int j = 0; j < 16; ++j) {
      const float4 b4 = *(const float4*)&BuCu[16 + t - j][4*p];
      float s = pw0*b4.x + pw1*b4.y + pw2*b4.z + pw3*b4.w;
      s += __shfl_xor(s, 1, 64);
      s += __shfl_xor(s, 2, 64);
      s += __shfl_xor(s, 4, 64);
      s += __shfl_xor(s, 8, 64);
      if (p == 0) KwS[t][j] = s;
      pw0 *= aa.x; pw1 *= aa.y; pw2 *= aa.z; pw3 *= aa.w;
    }
  }
  __syncthreads();
  if (tid < 64) {                               // coalesced 1 KB Kw write
    const int t = tid >> 2, jq = tid & 3;
    *(float4*)(Kwg + ((size_t)b * LS + t0 + t) * 16 + 4*jq) =
        *(const float4*)&KwS[t][4*jq];
  }
}

// ---------------------------------------------------------------------------
// KC v5 (unchanged): conv(W=16) + u*D + RMSNorm from u + Kw only.
// 512 blocks x 512 thr (2/CU), t-tile 16, ~2 KB LDS.
// ---------------------------------------------------------------------------
__global__ __launch_bounds__(512) void kc(const float* __restrict__ u,
                                          const float* __restrict__ Kwg,
                                          const float* __restrict__ Dv,
                                          const float* __restrict__ nw,
                                          float* __restrict__ out) {
  const int wg = blockIdx.x;                    // 0..511
  const int sw = (wg & 7) * 64 + (wg >> 3);     // chunked XCD swizzle
  const int b  = sw >> 7;
  const int t0 = (sw & 127) * 16;
  const int tid  = threadIdx.x;
  const int lane = tid & 63;
  const int w    = tid >> 6;
  const float* ub = u + (size_t)b * DM * LS;
  float* ob = out + (size_t)b * DM * LS;

  __shared__ float KwS[16][20];
  __shared__ float SSr[8][16];
  __shared__ float rsqv[16];

  if (tid < 64) {                               // stage Kw tile (1 KB, coalesced)
    const int t = tid >> 2, jq = tid & 3;
    *(float4*)&KwS[t][4*jq] =
        *(const float4*)(Kwg + ((size_t)b * LS + t0 + t) * 16 + 4*jq);
  }
  __syncthreads();

  // ---- conv + u*D, y in registers ----
  const int tg = tid & 3;
  const int dr = tid >> 2;                      // 0..127
  const int cbase = t0 - 16 + 4*tg;
  float y[8][4];
  float ps[4] = {0.f, 0.f, 0.f, 0.f};
  #pragma unroll 1
  for (int c = 0; c < 8; ++c) {
    const int d = dr + 128*c;
    const float* rowp = ub + (size_t)d * LS;
    float wr[20];
    #pragma unroll
    for (int s5 = 0; s5 < 5; ++s5) {
      int g = cbase + 4*s5;
      float4 v = (g >= 0) ? *(const float4*)(rowp + g)
                          : make_float4(0.f, 0.f, 0.f, 0.f);
      wr[4*s5+0] = v.x; wr[4*s5+1] = v.y; wr[4*s5+2] = v.z; wr[4*s5+3] = v.w;
    }
    const float Dd = Dv[d];
    #pragma unroll
    for (int k = 0; k < 4; ++k) {
      f32x4 kv0 = *(const f32x4*)&KwS[4*tg + k][0];   // broadcast b128 reads
      f32x4 kv1 = *(const f32x4*)&KwS[4*tg + k][4];
      f32x4 kv2 = *(const f32x4*)&KwS[4*tg + k][8];
      f32x4 kv3 = *(const f32x4*)&KwS[4*tg + k][12];
      float acc = wr[16 + k] * Dd;                    // skip connection u*D
      #pragma unroll
      for (int j = 0; j < 4; ++j)  acc = fmaf(kv0[j], wr[16 + k - j],      acc);
      #pragma unroll
      for (int j = 0; j < 4; ++j)  acc = fmaf(kv1[j], wr[16 + k - (j+4)],  acc);
      #pragma unroll
      for (int j = 0; j < 4; ++j)  acc = fmaf(kv2[j], wr[16 + k - (j+8)],  acc);
      #pragma unroll
      for (int j = 0; j < 4; ++j)  acc = fmaf(kv3[j], wr[16 + k - (j+12)], acc);
      y[c][k] = acc;
      ps[k] = fmaf(acc, acc, ps[k]);
    }
  }

  // ---- RMS reduce over d ----
  #pragma unroll
  for (int k = 0; k < 4; ++k) {
    ps[k] += __shfl_xor(ps[k], 4, 64);
    ps[k] += __shfl_xor(ps[k], 8, 64);
    ps[k] += __shfl_xor(ps[k], 16, 64);
    ps[k] += __shfl_xor(ps[k], 32, 64);
  }
  if (lane < 4)                                 // lane == tg holds t = 4*lane+k
    *(float4*)&SSr[w][4*lane] = make_float4(ps[0], ps[1], ps[2], ps[3]);
  __syncthreads();
  if (tid < 16) {
    float s = 0.f;
    #pragma unroll
    for (int ww = 0; ww < 8; ++ww) s += SSr[ww][tid];
    rsqv[tid] = rsqrtf(s * (1.f/1024.f) + RMS_EPS);
  }
  __syncthreads();

  // ---- normalize + store ----
  float rq[4];
  #pragma unroll
  for (int k = 0; k < 4; ++k) rq[k] = rsqv[4*tg + k];
  #pragma unroll 1
  for (int c = 0; c < 8; ++c) {
    const int d = dr + 128*c;
    const float wn2 = nw[d];
    float4 o;
    o.x = y[c][0] * rq[0] * wn2;
    o.y = y[c][1] * rq[1] * wn2;
    o.z = y[c][2] * rq[2] * wn2;
    o.w = y[c][3] * rq[3] * wn2;
    *(float4*)(ob + (size_t)d * LS + t0 + 4*tg) = o;
  }
}

// ---------------------------------------------------------------------------
extern "C" void kernel_launch(void* const* d_in, const int* in_sizes, int n_in,
                              void* d_out, int out_size, void* d_ws, size_t ws_size,
                              hipStream_t stream) {
  // inputs: [0]=L(int,1), [1]=u, [2]=A, [3]=B, [4]=C, [5]=D, [6]=norm_w
  const float* u  = (const float*)d_in[1];
  const float* A  = (const float*)d_in[2];
  const float* B  = (const float*)d_in[3];
  const float* C  = (const float*)d_in[4];
  const float* Dv = (const float*)d_in[5];
  const float* nw = (const float*)d_in[6];
  float* out = (float*)d_out;

  float* Kwg = (float*)d_ws;                                         // 512 KB
  unsigned short* Bbf = (unsigned short*)((char*)d_ws + (512u << 10)); // 256 KB

  k0_prep<<<dim3(128), dim3(256), 0, stream>>>(B, C, Bbf);
  kg     <<<dim3(512), dim3(256), 0, stream>>>(u, Bbf, A, Kwg);
  kc     <<<dim3(512), dim3(512), 0, stream>>>(u, Kwg, Dv, nw, out);
}